// Round 1
// baseline (83371.295 us; speedup 1.0000x reference)
//
#include <hip/hip_runtime.h>
#include <math.h>

#define Bsz 64
#define Tlen 600
#define Hd 512
#define Vv 33
#define Ssteps 250
#define NBLK 256
#define NTHR 512
#define NWAVE 8
#define HB (Hd*Bsz)   // 32768

// workspace offsets (in floats)
#define OFF_ENERGY 0
#define OFF_CTXT   38400
#define OFF_EMBT   (OFF_CTXT + HB)
#define OFF_H0T    (OFF_EMBT + HB)
#define OFF_H1T    (OFF_H0T + 2*HB)
#define OFF_H2T    (OFF_H1T + 2*HB)
#define OFF_C0T    (OFF_H2T + 2*HB)
#define OFF_C1T    (OFF_C0T + HB)
#define OFF_C2T    (OFF_C1T + HB)
#define OFF_H2N    (OFF_C2T + HB)
#define OFF_ZN     (OFF_H2N + HB)
#define OFF_CNT    (OFF_ZN + HB)

__device__ __forceinline__ float sigm(float x) { return 1.0f / (1.0f + expf(-x)); }

// Monotonic grid barrier. All 256 blocks are guaranteed resident (256 blocks
// <= min capacity), so spin-wait is deadlock-free with a plain launch.
__device__ __forceinline__ void gridbar(int* cnt, int& epoch) {
  __syncthreads();
  if (threadIdx.x == 0) {
    __threadfence();
    __hip_atomic_fetch_add(cnt, 1, __ATOMIC_ACQ_REL, __HIP_MEMORY_SCOPE_AGENT);
    int tgt = (epoch + 1) * (int)gridDim.x;
    while (__hip_atomic_load(cnt, __ATOMIC_ACQUIRE, __HIP_MEMORY_SCOPE_AGENT) < tgt)
      __builtin_amdgcn_s_sleep(1);
    __threadfence();
  }
  epoch++;
  __syncthreads();
}

// energy[b][t] = dot(L[b][t][:], h2n[b][:]) masked by seq len
__device__ void phase_energy(const float* __restrict__ L, const int* __restrict__ seqs,
                             const float* __restrict__ h2n, float* __restrict__ energy,
                             int nBlkE) {
  int blk = blockIdx.x;
  if (blk >= nBlkE) return;
  int wid = blk * NWAVE + (threadIdx.x >> 6);
  int lane = threadIdx.x & 63;
  int b = wid & 63;
  int tstep = (nBlkE * NWAVE) >> 6;
  int k0 = lane * 8;
  const float4* hr = (const float4*)(h2n + (size_t)b * Hd + k0);
  float4 hv0 = hr[0], hv1 = hr[1];
  int sq = seqs[b];
  for (int t = wid >> 6; t < Tlen; t += tstep) {
    const float4* Lr = (const float4*)(L + ((size_t)b * Tlen + t) * Hd + k0);
    float4 a0 = Lr[0], a1 = Lr[1];
    float d = a0.x*hv0.x + a0.y*hv0.y + a0.z*hv0.z + a0.w*hv0.w
            + a1.x*hv1.x + a1.y*hv1.y + a1.z*hv1.z + a1.w*hv1.w;
    #pragma unroll
    for (int off = 32; off > 0; off >>= 1) d += __shfl_xor(d, off, 64);
    if (lane == 0) energy[b * Tlen + t] = (t < sq) ? d : -1e9f;
  }
}

// softmax (recomputed per block, cheap) + context for a 128-wide h chunk.
// hc==0 blocks also write the attention output row.
__device__ void phase_context(const float* __restrict__ L, const float* __restrict__ energy,
                              float* __restrict__ ctxT, float* __restrict__ attnRow,
                              float* smem, int b, int hc) {
  float* p    = smem;        // 600
  float* red  = smem + 608;  // 8
  float* cred = smem + 640;  // 512
  int tid = threadIdx.x, lane = tid & 63, wv = tid >> 6;
  const float* er = energy + b * Tlen;
  float m = -1e30f;
  for (int t = tid; t < Tlen; t += NTHR) m = fmaxf(m, er[t]);
  #pragma unroll
  for (int off = 32; off > 0; off >>= 1) m = fmaxf(m, __shfl_xor(m, off, 64));
  if (lane == 0) red[wv] = m;
  __syncthreads();
  m = red[0];
  #pragma unroll
  for (int i = 1; i < NWAVE; ++i) m = fmaxf(m, red[i]);
  __syncthreads();   // done reading red before reuse
  float ss = 0.f;
  for (int t = tid; t < Tlen; t += NTHR) { float pv = expf(er[t] - m); p[t] = pv; ss += pv; }
  #pragma unroll
  for (int off = 32; off > 0; off >>= 1) ss += __shfl_xor(ss, off, 64);
  if (lane == 0) red[wv] = ss;
  __syncthreads();
  ss = red[0];
  #pragma unroll
  for (int i = 1; i < NWAVE; ++i) ss += red[i];
  float inv = 1.0f / ss;
  if (hc == 0 && attnRow) {
    for (int t = tid; t < Tlen; t += NTHR) attnRow[t] = p[t] * inv;
  }
  int h = hc * 128 + (tid & 127);
  int tg = tid >> 7;   // 4 t-groups
  float acc = 0.f;
  for (int t = tg; t < Tlen; t += 4) acc += p[t] * L[((size_t)b * Tlen + t) * Hd + h];
  cred[tg * 128 + (tid & 127)] = acc;
  __syncthreads();
  if (tid < 128) {
    float c = (cred[tid] + cred[128 + tid] + cred[256 + tid] + cred[384 + tid]) * inv;
    ctxT[(hc * 128 + tid) * Bsz + b] = c;
  }
}

// One LSTM cell. Block owns 2 h-columns (8 gate rows: j = gate*512 + h0 + hh),
// all 64 b in lanes. 8 waves k-split; in-block reduce + gate combine.
// x sources are transposed [k][b]; weights read with uniform (scalar) indices.
template<int KTOT, int KIH>
__device__ void phase_lstm(const float* __restrict__ xA, int kA,
                           const float* __restrict__ xB, int kB,
                           const float* __restrict__ xC,
                           const float* __restrict__ wih, const float* __restrict__ whh,
                           const float* __restrict__ bih, const float* __restrict__ bhh,
                           float* __restrict__ cT, float* __restrict__ hTout,
                           float* __restrict__ hNout, float* smem) {
  int h0 = blockIdx.x * 2;
  int wv = threadIdx.x >> 6, lane = threadIdx.x & 63;
  const int Kc = KTOT / NWAVE;
  int kLo = wv * Kc;
  float acc[8] = {0,0,0,0,0,0,0,0};
  for (int kq = kLo; kq < kLo + Kc; kq += 4) {
    const float* xs; int kk;
    if (kq < kA)      { xs = xA; kk = kq; }
    else if (kq < kB) { xs = xB; kk = kq - kA; }
    else              { xs = xC; kk = kq - kB; }
    float x0 = xs[kk*Bsz + lane];
    float x1 = xs[(kk+1)*Bsz + lane];
    float x2 = xs[(kk+2)*Bsz + lane];
    float x3 = xs[(kk+3)*Bsz + lane];
    const float* wb_; int kw, Kw;
    if (kq < KIH) { wb_ = wih; kw = kq;       Kw = KIH; }
    else          { wb_ = whh; kw = kq - KIH; Kw = Hd;  }
    #pragma unroll
    for (int jj = 0; jj < 8; ++jj) {
      int j = (jj >> 1) * Hd + h0 + (jj & 1);
      const float4 w4 = *(const float4*)(wb_ + (size_t)j * Kw + kw);
      acc[jj] = fmaf(w4.w, x3, fmaf(w4.z, x2, fmaf(w4.y, x1, fmaf(w4.x, x0, acc[jj]))));
    }
  }
  float* lred = smem;           // [8 waves][8 jj][64 b]
  float* gv   = smem + 4096;    // [8 jj][64 b]
  #pragma unroll
  for (int jj = 0; jj < 8; ++jj) lred[wv*512 + jj*64 + lane] = acc[jj];
  __syncthreads();
  int jj2 = threadIdx.x >> 6, b2 = threadIdx.x & 63;
  float g = 0.f;
  #pragma unroll
  for (int w = 0; w < NWAVE; ++w) g += lred[w*512 + jj2*64 + b2];
  int j2 = (jj2 >> 1) * Hd + h0 + (jj2 & 1);
  g += bih[j2] + bhh[j2];
  gv[jj2 * 64 + b2] = g;
  __syncthreads();
  if (threadIdx.x < 128) {
    int hh = threadIdx.x >> 6, b3 = threadIdx.x & 63;
    float gi = sigm (gv[(0*2+hh)*64 + b3]);
    float gf = sigm (gv[(1*2+hh)*64 + b3]);
    float gg = tanhf(gv[(2*2+hh)*64 + b3]);
    float go = sigm (gv[(3*2+hh)*64 + b3]);
    int h = h0 + hh;
    float c = cT[h*Bsz + b3];
    float c2 = gf * c + gi * gg;
    float hv = go * tanhf(c2);
    cT[h*Bsz + b3] = c2;
    hTout[h*Bsz + b3] = hv;
    if (hNout) hNout[(size_t)b3 * Hd + h] = hv;
  }
}

// z = LeakyReLU(fc([h2', ctx])) for 8 contiguous rows per block (blocks 192..255)
__device__ void phase_fcz(const float* __restrict__ h2T, const float* __restrict__ ctxT,
                          const float* __restrict__ fcW, const float* __restrict__ fcB,
                          float* __restrict__ zn, float* smem) {
  int i0 = (blockIdx.x - 192) * 8;
  int wv = threadIdx.x >> 6, lane = threadIdx.x & 63;
  const int Kc = 1024 / NWAVE;  // 128
  int kLo = wv * Kc;
  float acc[8] = {0,0,0,0,0,0,0,0};
  for (int kq = kLo; kq < kLo + Kc; kq += 4) {
    const float* xs; int kk;
    if (kq < 512) { xs = h2T; kk = kq; } else { xs = ctxT; kk = kq - 512; }
    float x0 = xs[kk*Bsz + lane], x1 = xs[(kk+1)*Bsz + lane];
    float x2 = xs[(kk+2)*Bsz + lane], x3 = xs[(kk+3)*Bsz + lane];
    #pragma unroll
    for (int jj = 0; jj < 8; ++jj) {
      const float4 w4 = *(const float4*)(fcW + (size_t)(i0 + jj) * 1024 + kq);
      acc[jj] = fmaf(w4.w, x3, fmaf(w4.z, x2, fmaf(w4.y, x1, fmaf(w4.x, x0, acc[jj]))));
    }
  }
  float* lred = smem;
  #pragma unroll
  for (int jj = 0; jj < 8; ++jj) lred[wv*512 + jj*64 + lane] = acc[jj];
  __syncthreads();
  int jj2 = threadIdx.x >> 6, b2 = threadIdx.x & 63;
  float z = 0.f;
  #pragma unroll
  for (int w = 0; w < NWAVE; ++w) z += lred[w*512 + jj2*64 + b2];
  z += fcB[i0 + jj2];
  z = (z >= 0.f) ? z : 0.2f * z;
  zn[(size_t)b2 * Hd + (i0 + jj2)] = z;
}

// logits + argmax + preds write + next-step embT build, all in one block (per b)
__device__ void phase_pred(const float* __restrict__ zn, const float* __restrict__ embW,
                           const float* __restrict__ unembB, float* __restrict__ out,
                           float* __restrict__ embT, int s, int b, float* smem) {
  __syncthreads();   // smem reuse guard (context may have used it in this window)
  float* pl = smem;               // 33 logits
  int* pw = (int*)(smem + 64);
  int tid = threadIdx.x, lane = tid & 63, wv = tid >> 6;
  const float4* zr = (const float4*)(zn + (size_t)b * Hd + lane * 8);
  float4 z0 = zr[0], z1 = zr[1];
  for (int v = wv; v < Vv; v += NWAVE) {
    const float4* er = (const float4*)(embW + (size_t)v * Hd + lane * 8);
    float4 e0 = er[0], e1 = er[1];
    float d = z0.x*e0.x + z0.y*e0.y + z0.z*e0.z + z0.w*e0.w
            + z1.x*e1.x + z1.y*e1.y + z1.z*e1.z + z1.w*e1.w;
    #pragma unroll
    for (int off = 32; off > 0; off >>= 1) d += __shfl_xor(d, off, 64);
    if (lane == 0) pl[v] = d + unembB[v];
  }
  __syncthreads();
  if (tid == 0) {
    int best = 0; float bv = pl[0];
    for (int v = 1; v < Vv; ++v) { if (pl[v] > bv) { bv = pl[v]; best = v; } }
    *pw = best;
  }
  __syncthreads();
  int wsel = *pw;
  if (tid < Vv) out[(size_t)b * Ssteps * Vv + (size_t)s * Vv + tid] = pl[tid];
  embT[tid * Bsz + b] = embW[(size_t)wsel * Hd + tid];   // NTHR == Hd
}

extern "C" __global__ void __launch_bounds__(NTHR)
speller_kernel(const float* __restrict__ L, const int* __restrict__ seqs,
               const float* __restrict__ embW, const float* __restrict__ unembB,
               const float* __restrict__ fcW, const float* __restrict__ fcB,
               const float* __restrict__ wih0, const float* __restrict__ whh0,
               const float* __restrict__ bih0, const float* __restrict__ bhh0,
               const float* __restrict__ ih0, const float* __restrict__ ic0,
               const float* __restrict__ wih1, const float* __restrict__ whh1,
               const float* __restrict__ bih1, const float* __restrict__ bhh1,
               const float* __restrict__ ih1, const float* __restrict__ ic1,
               const float* __restrict__ wih2, const float* __restrict__ whh2,
               const float* __restrict__ bih2, const float* __restrict__ bhh2,
               const float* __restrict__ ih2, const float* __restrict__ ic2,
               float* __restrict__ out, float* __restrict__ ws) {
  __shared__ float smem[4608];
  int epoch = 0;
  float* energy = ws + OFF_ENERGY;
  float* ctxT = ws + OFF_CTXT;
  float* embT = ws + OFF_EMBT;
  float* h0T = ws + OFF_H0T;
  float* h1T = ws + OFF_H1T;
  float* h2T = ws + OFF_H2T;
  float* c0T = ws + OFF_C0T;
  float* c1T = ws + OFF_C1T;
  float* c2T = ws + OFF_C2T;
  float* h2n = ws + OFF_H2N;
  float* zn  = ws + OFF_ZN;
  int* cnt   = (int*)(ws + OFF_CNT);
  float* attnBase = out + (size_t)Bsz * Ssteps * Vv;

  // ---- init: word=0 embedding, tiled init states (transposed layouts) ----
  {
    int gid = blockIdx.x * NTHR + threadIdx.x;
    for (int i = gid; i < HB; i += NBLK * NTHR) {
      int k = i >> 6;            // i = k*64 + b
      embT[i]      = embW[k];    // embed_w[word=0][k]
      h0T[HB + i]  = ih0[k];     // read-buffer for s=0 (parity 1)
      h1T[HB + i]  = ih1[k];
      h2T[HB + i]  = ih2[k];
      c0T[i] = ic0[k];
      c1T[i] = ic1[k];
      c2T[i] = ic2[k];
      h2n[i] = ih2[i & (Hd - 1)]; // [b][h]
    }
  }
  gridbar(cnt, epoch);
  // ---- prologue: E(0), C(0) ----
  phase_energy(L, seqs, h2n, energy, NBLK);
  gridbar(cnt, epoch);
  {
    int b = blockIdx.x & 63, hc = blockIdx.x >> 6;
    phase_context(L, energy, ctxT,
                  (hc == 0) ? (attnBase + (size_t)b * Ssteps * Tlen) : nullptr,
                  smem, b, hc);
  }
  gridbar(cnt, epoch);

  for (int s = 0; s < Ssteps; ++s) {
    int wb = (s & 1), rb = wb ^ 1;
    // W1: LSTM layer 0, K = [emb | ctx | h0]
    phase_lstm<1536,1024>(embT, 512, ctxT, 1024, h0T + rb*HB,
                          wih0, whh0, bih0, bhh0, c0T, h0T + wb*HB, nullptr, smem);
    gridbar(cnt, epoch);
    // W2: LSTM layer 1, K = [h0' | h1]
    phase_lstm<1024,512>(h0T + wb*HB, 512, h1T + rb*HB, 1024, nullptr,
                         wih1, whh1, bih1, bhh1, c1T, h1T + wb*HB, nullptr, smem);
    gridbar(cnt, epoch);
    // W3: LSTM layer 2, K = [h1' | h2]; also emits h2 in [b][h] layout for E
    phase_lstm<1024,512>(h1T + wb*HB, 512, h2T + rb*HB, 1024, nullptr,
                         wih2, whh2, bih2, bhh2, c2T, h2T + wb*HB, h2n, smem);
    gridbar(cnt, epoch);
    // W4: fc-z(s) on blocks 192..255  ||  energy(s+1) on blocks 0..191
    if (blockIdx.x >= 192) phase_fcz(h2T + wb*HB, ctxT, fcW, fcB, zn, smem);
    else if (s + 1 < Ssteps) phase_energy(L, seqs, h2n, energy, 192);
    gridbar(cnt, epoch);
    // W5: context(s+1) on all blocks  ||  pred+argmax(s) on hc==0 blocks
    {
      int b = blockIdx.x & 63, hc = blockIdx.x >> 6;
      if (s + 1 < Ssteps)
        phase_context(L, energy, ctxT,
                      (hc == 0) ? (attnBase + (size_t)b * Ssteps * Tlen + (size_t)(s+1) * Tlen)
                                : nullptr,
                      smem, b, hc);
      if (hc == 0) phase_pred(zn, embW, unembB, out, embT, s, b, smem);
    }
    gridbar(cnt, epoch);
  }
}

extern "C" void kernel_launch(void* const* d_in, const int* in_sizes, int n_in,
                              void* d_out, int out_size, void* d_ws, size_t ws_size,
                              hipStream_t stream) {
  if (ws_size < (size_t)(OFF_CNT + 16) * 4) return;
  const float* L      = (const float*)d_in[0];
  const int*   seqs   = (const int*)d_in[1];
  // d_in[2] = max_iters (constant 250)
  const float* embW   = (const float*)d_in[3];
  const float* unembB = (const float*)d_in[4];
  const float* fcW    = (const float*)d_in[5];
  const float* fcB    = (const float*)d_in[6];
  const float* wih0 = (const float*)d_in[7];
  const float* whh0 = (const float*)d_in[8];
  const float* bih0 = (const float*)d_in[9];
  const float* bhh0 = (const float*)d_in[10];
  const float* ih0  = (const float*)d_in[11];
  const float* ic0  = (const float*)d_in[12];
  const float* wih1 = (const float*)d_in[13];
  const float* whh1 = (const float*)d_in[14];
  const float* bih1 = (const float*)d_in[15];
  const float* bhh1 = (const float*)d_in[16];
  const float* ih1  = (const float*)d_in[17];
  const float* ic1  = (const float*)d_in[18];
  const float* wih2 = (const float*)d_in[19];
  const float* whh2 = (const float*)d_in[20];
  const float* bih2 = (const float*)d_in[21];
  const float* bhh2 = (const float*)d_in[22];
  const float* ih2  = (const float*)d_in[23];
  const float* ic2  = (const float*)d_in[24];
  float* out = (float*)d_out;
  float* ws  = (float*)d_ws;
  hipMemsetAsync((char*)d_ws + (size_t)OFF_CNT * 4, 0, 64, stream);
  hipLaunchKernelGGL(speller_kernel, dim3(NBLK), dim3(NTHR), 0, stream,
                     L, seqs, embW, unembB, fcW, fcB,
                     wih0, whh0, bih0, bhh0, ih0, ic0,
                     wih1, whh1, bih1, bhh1, ih1, ic1,
                     wih2, whh2, bih2, bhh2, ih2, ic2,
                     out, ws);
}

// Round 2
// 76586.023 us; speedup vs baseline: 1.0886x; 1.0886x over previous
//
#include <hip/hip_runtime.h>
#include <math.h>

#define Bsz 64
#define Tlen 600
#define Hd 512
#define Vv 33
#define Ssteps 250
#define NBLK 256
#define NTHR 512
#define NWAVE 8
#define HB (Hd*Bsz)   // 32768
#define FAB 192       // fused-attention blocks (3 per b)
#define TCH 200       // t-chunk per attention block

// workspace offsets (floats)
#define OFF_ENERGY 0
#define OFF_CTXQ   38400
#define OFF_EMBQ   (OFF_CTXQ + HB)
#define OFF_H0Q    (OFF_EMBQ + HB)
#define OFF_H1Q    (OFF_H0Q + 2*HB)
#define OFF_H2Q    (OFF_H1Q + 2*HB)
#define OFF_C0     (OFF_H2Q + 2*HB)
#define OFF_C1     (OFF_C0 + HB)
#define OFF_C2     (OFF_C1 + HB)
#define OFF_H2N    (OFF_C2 + HB)
#define OFF_ZN     (OFF_H2N + HB)
#define OFF_CTXP   (OFF_ZN + HB)        // FAB*512
#define OFF_MP     (OFF_CTXP + FAB*Hd)  // FAB
#define OFF_SP     (OFF_MP + FAB)       // FAB
#define OFF_CNT    (OFF_SP + FAB)

__device__ __forceinline__ float sigm(float x) { return 1.0f / (1.0f + expf(-x)); }

// Monotonic grid barrier; 256 blocks guaranteed co-resident.
__device__ __forceinline__ void gridbar(int* cnt, int& epoch) {
  __syncthreads();
  if (threadIdx.x == 0) {
    __threadfence();
    __hip_atomic_fetch_add(cnt, 1, __ATOMIC_ACQ_REL, __HIP_MEMORY_SCOPE_AGENT);
    int tgt = (epoch + 1) * (int)gridDim.x;
    while (__hip_atomic_load(cnt, __ATOMIC_ACQUIRE, __HIP_MEMORY_SCOPE_AGENT) < tgt)
      __builtin_amdgcn_s_sleep(1);
    __threadfence();
  }
  epoch++;
  __syncthreads();
}

// Fused energy + online-softmax + context partials. Block = (b, chunk of 200 t).
// Each wave: 25 t rows, row loaded once as 2xfloat4, used for dot AND context.
__device__ void phase_attn(const float* __restrict__ L, const int* __restrict__ seqs,
                           const float* __restrict__ h2n, float* __restrict__ energy,
                           float* __restrict__ ctxP, float* __restrict__ mP,
                           float* __restrict__ sP, float* smem) {
  int blk = blockIdx.x;
  if (blk >= FAB) return;
  int b = blk & 63, ch = blk >> 6;
  int wv = threadIdx.x >> 6, lane = threadIdx.x & 63;
  int k0 = lane * 8;
  const float4* hq = (const float4*)(h2n + (size_t)b * Hd + k0);
  float4 q0 = hq[0], q1 = hq[1];
  int sq = seqs[b];
  float m = -1e30f, ss = 0.f;
  float4 ca0 = {0,0,0,0}, ca1 = {0,0,0,0};
  int tEnd = ch * TCH + TCH;
  for (int t = ch * TCH + wv; t < tEnd; t += NWAVE) {
    if (t < sq) {
      const float4* Lr = (const float4*)(L + ((size_t)b * Tlen + t) * Hd + k0);
      float4 a0 = Lr[0], a1 = Lr[1];
      float d = a0.x*q0.x + a0.y*q0.y + a0.z*q0.z + a0.w*q0.w
              + a1.x*q1.x + a1.y*q1.y + a1.z*q1.z + a1.w*q1.w;
      #pragma unroll
      for (int off = 32; off > 0; off >>= 1) d += __shfl_xor(d, off, 64);
      if (lane == 0) energy[b * Tlen + t] = d;
      float m2 = fmaxf(m, d);
      float sc = expf(m - m2);
      float p = expf(d - m2);
      ss = ss * sc + p;
      ca0.x = ca0.x*sc + p*a0.x; ca0.y = ca0.y*sc + p*a0.y;
      ca0.z = ca0.z*sc + p*a0.z; ca0.w = ca0.w*sc + p*a0.w;
      ca1.x = ca1.x*sc + p*a1.x; ca1.y = ca1.y*sc + p*a1.y;
      ca1.z = ca1.z*sc + p*a1.z; ca1.w = ca1.w*sc + p*a1.w;
      m = m2;
    } else {
      if (lane == 0) energy[b * Tlen + t] = -1e9f;
    }
  }
  // in-block combine of 8 wave partials
  float* mW = smem;        // 8
  float* sW = smem + 8;    // 8
  float* cL = smem + 16;   // 8*512
  if (lane == 0) { mW[wv] = m; sW[wv] = ss; }
  *(float4*)(cL + wv * Hd + k0) = ca0;
  *(float4*)(cL + wv * Hd + k0 + 4) = ca1;
  __syncthreads();
  int h = threadIdx.x;
  float M = mW[0];
  #pragma unroll
  for (int w = 1; w < NWAVE; ++w) M = fmaxf(M, mW[w]);
  float S = 0.f, cx = 0.f;
  #pragma unroll
  for (int w = 0; w < NWAVE; ++w) {
    float e = expf(mW[w] - M);
    S += e * sW[w];
    cx += e * cL[w * Hd + h];
  }
  ctxP[(size_t)blk * Hd + h] = cx;
  if (threadIdx.x == 0) { mP[blk] = M; sP[blk] = S; }
}

// Combine 3 chunk-partials per b -> ctxQ (quad layout) + attention output row.
__device__ void phase_combine(const float* __restrict__ energy, const float* __restrict__ ctxP,
                              const float* __restrict__ mP, const float* __restrict__ sP,
                              float* __restrict__ ctxQ, float* __restrict__ attnRow) {
  int b = blockIdx.x;   // caller guarantees < 64
  float m0 = mP[b], m1 = mP[64 + b], m2 = mP[128 + b];
  float M = fmaxf(m0, fmaxf(m1, m2));
  float e0 = expf(m0 - M), e1 = expf(m1 - M), e2 = expf(m2 - M);
  float S = e0 * sP[b] + e1 * sP[64 + b] + e2 * sP[128 + b];
  float inv = 1.0f / S;
  int h = threadIdx.x;
  float cx = e0 * ctxP[((size_t)b) * Hd + h]
           + e1 * ctxP[((size_t)(64 + b)) * Hd + h]
           + e2 * ctxP[((size_t)(128 + b)) * Hd + h];
  ctxQ[((h >> 2) * 64 + b) * 4 + (h & 3)] = cx * inv;
  for (int t = threadIdx.x; t < Tlen; t += NTHR)
    attnRow[t] = expf(energy[b * Tlen + t] - M) * inv;
}

// LSTM cell. Block owns 2 h-columns (8 gate rows), lanes = batch. Quad-packed
// x sources [k/4][b][4]; wave-uniform weight addresses via readfirstlane.
template<int KTOT, int KIH>
__device__ void phase_lstm(const float* __restrict__ xA, int kA,
                           const float* __restrict__ xB, int kB,
                           const float* __restrict__ xC,
                           const float* __restrict__ wih, const float* __restrict__ whh,
                           const float* __restrict__ bih, const float* __restrict__ bhh,
                           float* __restrict__ cT, float* __restrict__ hQout,
                           float* __restrict__ hNout, float* smem) {
  int h0 = blockIdx.x * 2;
  int wv = threadIdx.x >> 6, lane = threadIdx.x & 63;
  int wvu = __builtin_amdgcn_readfirstlane(wv);
  const int Kc = KTOT / NWAVE;
  int kLo = wvu * Kc;
  float acc[8] = {0,0,0,0,0,0,0,0};
  for (int kq = kLo; kq < kLo + Kc; kq += 4) {
    const float* xs; int kk;
    if (kq < kA)      { xs = xA; kk = kq; }
    else if (kq < kB) { xs = xB; kk = kq - kA; }
    else              { xs = xC; kk = kq - kB; }
    float4 xv = *(const float4*)(xs + (size_t)(kk >> 2) * 256 + lane * 4);
    const float* wb_; int kw, Kw;
    if (kq < KIH) { wb_ = wih; kw = kq;       Kw = KIH; }
    else          { wb_ = whh; kw = kq - KIH; Kw = Hd;  }
    #pragma unroll
    for (int jj = 0; jj < 8; ++jj) {
      int j = (jj >> 1) * Hd + h0 + (jj & 1);
      const float4 w4 = *(const float4*)(wb_ + (size_t)j * Kw + kw);
      acc[jj] = fmaf(w4.w, xv.w, fmaf(w4.z, xv.z, fmaf(w4.y, xv.y, fmaf(w4.x, xv.x, acc[jj]))));
    }
  }
  float* lred = smem;           // [8 waves][8 jj][64 b]
  float* gv   = smem + 4096;    // [8 jj][64 b]
  #pragma unroll
  for (int jj = 0; jj < 8; ++jj) lred[wv*512 + jj*64 + lane] = acc[jj];
  __syncthreads();
  int jj2 = threadIdx.x >> 6, b2 = threadIdx.x & 63;
  float g = 0.f;
  #pragma unroll
  for (int w = 0; w < NWAVE; ++w) g += lred[w*512 + jj2*64 + b2];
  int j2 = (jj2 >> 1) * Hd + h0 + (jj2 & 1);
  g += bih[j2] + bhh[j2];
  gv[jj2 * 64 + b2] = g;
  __syncthreads();
  if (threadIdx.x < 128) {
    int hh = threadIdx.x >> 6, b3 = threadIdx.x & 63;
    float gi = sigm (gv[(0*2+hh)*64 + b3]);
    float gf = sigm (gv[(1*2+hh)*64 + b3]);
    float gg = tanhf(gv[(2*2+hh)*64 + b3]);
    float go = sigm (gv[(3*2+hh)*64 + b3]);
    int h = h0 + hh;
    float c = cT[h*Bsz + b3];
    float c2 = gf * c + gi * gg;
    float hv = go * tanhf(c2);
    cT[h*Bsz + b3] = c2;
    hQout[((h >> 2) * 64 + b3) * 4 + (h & 3)] = hv;
    if (hNout) hNout[(size_t)b3 * Hd + h] = hv;
  }
}

// z = LeakyReLU(fc([h2', ctx])), 8 rows per block (blocks 192..255)
__device__ void phase_fcz(const float* __restrict__ h2Q, const float* __restrict__ ctxQ,
                          const float* __restrict__ fcW, const float* __restrict__ fcB,
                          float* __restrict__ zn, float* smem) {
  int i0 = (blockIdx.x - 192) * 8;
  int wv = threadIdx.x >> 6, lane = threadIdx.x & 63;
  int wvu = __builtin_amdgcn_readfirstlane(wv);
  const int Kc = 1024 / NWAVE;  // 128
  int kLo = wvu * Kc;
  float acc[8] = {0,0,0,0,0,0,0,0};
  for (int kq = kLo; kq < kLo + Kc; kq += 4) {
    const float* xs; int kk;
    if (kq < 512) { xs = h2Q; kk = kq; } else { xs = ctxQ; kk = kq - 512; }
    float4 xv = *(const float4*)(xs + (size_t)(kk >> 2) * 256 + lane * 4);
    #pragma unroll
    for (int jj = 0; jj < 8; ++jj) {
      const float4 w4 = *(const float4*)(fcW + (size_t)(i0 + jj) * 1024 + kq);
      acc[jj] = fmaf(w4.w, xv.w, fmaf(w4.z, xv.z, fmaf(w4.y, xv.y, fmaf(w4.x, xv.x, acc[jj]))));
    }
  }
  float* lred = smem;
  #pragma unroll
  for (int jj = 0; jj < 8; ++jj) lred[wv*512 + jj*64 + lane] = acc[jj];
  __syncthreads();
  int jj2 = threadIdx.x >> 6, b2 = threadIdx.x & 63;
  float z = 0.f;
  #pragma unroll
  for (int w = 0; w < NWAVE; ++w) z += lred[w*512 + jj2*64 + b2];
  z += fcB[i0 + jj2];
  z = (z >= 0.f) ? z : 0.2f * z;
  zn[(size_t)b2 * Hd + (i0 + jj2)] = z;
}

// logits + argmax + preds write + next-step embQ build; blocks 64..127, b=blk-64
__device__ void phase_pred(const float* __restrict__ zn, const float* __restrict__ embW,
                           const float* __restrict__ unembB, float* __restrict__ out,
                           float* __restrict__ embQ, int s, int b, float* smem) {
  float* pl = smem;               // 33 logits
  int* pw = (int*)(smem + 64);
  int tid = threadIdx.x, lane = tid & 63, wv = tid >> 6;
  const float4* zr = (const float4*)(zn + (size_t)b * Hd + lane * 8);
  float4 z0 = zr[0], z1 = zr[1];
  for (int v = wv; v < Vv; v += NWAVE) {
    const float4* er = (const float4*)(embW + (size_t)v * Hd + lane * 8);
    float4 e0 = er[0], e1 = er[1];
    float d = z0.x*e0.x + z0.y*e0.y + z0.z*e0.z + z0.w*e0.w
            + z1.x*e1.x + z1.y*e1.y + z1.z*e1.z + z1.w*e1.w;
    #pragma unroll
    for (int off = 32; off > 0; off >>= 1) d += __shfl_xor(d, off, 64);
    if (lane == 0) pl[v] = d + unembB[v];
  }
  __syncthreads();
  if (tid == 0) {
    int best = 0; float bv = pl[0];
    for (int v = 1; v < Vv; ++v) { if (pl[v] > bv) { bv = pl[v]; best = v; } }
    *pw = best;
  }
  __syncthreads();
  int wsel = *pw;
  if (tid < Vv) out[(size_t)b * Ssteps * Vv + (size_t)s * Vv + tid] = pl[tid];
  embQ[((tid >> 2) * 64 + b) * 4 + (tid & 3)] = embW[(size_t)wsel * Hd + tid];
}

extern "C" __global__ void __launch_bounds__(NTHR)
speller_kernel(const float* __restrict__ L, const int* __restrict__ seqs,
               const float* __restrict__ embW, const float* __restrict__ unembB,
               const float* __restrict__ fcW, const float* __restrict__ fcB,
               const float* __restrict__ wih0, const float* __restrict__ whh0,
               const float* __restrict__ bih0, const float* __restrict__ bhh0,
               const float* __restrict__ ih0, const float* __restrict__ ic0,
               const float* __restrict__ wih1, const float* __restrict__ whh1,
               const float* __restrict__ bih1, const float* __restrict__ bhh1,
               const float* __restrict__ ih1, const float* __restrict__ ic1,
               const float* __restrict__ wih2, const float* __restrict__ whh2,
               const float* __restrict__ bih2, const float* __restrict__ bhh2,
               const float* __restrict__ ih2, const float* __restrict__ ic2,
               float* __restrict__ out, float* __restrict__ ws) {
  __shared__ float smem[4608];
  int epoch = 0;
  float* energy = ws + OFF_ENERGY;
  float* ctxQ = ws + OFF_CTXQ;
  float* embQ = ws + OFF_EMBQ;
  float* h0Q = ws + OFF_H0Q;
  float* h1Q = ws + OFF_H1Q;
  float* h2Q = ws + OFF_H2Q;
  float* c0T = ws + OFF_C0;
  float* c1T = ws + OFF_C1;
  float* c2T = ws + OFF_C2;
  float* h2n = ws + OFF_H2N;
  float* zn  = ws + OFF_ZN;
  float* ctxP = ws + OFF_CTXP;
  float* mP = ws + OFF_MP;
  float* sP = ws + OFF_SP;
  int* cnt  = (int*)(ws + OFF_CNT);
  float* attnBase = out + (size_t)Bsz * Ssteps * Vv;

  // init: word-0 embedding, init states (quad layouts for x-operands)
  {
    int gid = blockIdx.x * NTHR + threadIdx.x;
    for (int i = gid; i < HB; i += NBLK * NTHR) {
      int kq_ = (i >> 8) * 4 + (i & 3);   // quad-layout k for element i
      int h = i >> 6;                      // [h][b] layout index
      embQ[i]     = embW[kq_];
      h0Q[HB + i] = ih0[kq_];
      h1Q[HB + i] = ih1[kq_];
      h2Q[HB + i] = ih2[kq_];
      c0T[i] = ic0[h];
      c1T[i] = ic1[h];
      c2T[i] = ic2[h];
      h2n[i] = ih2[i & (Hd - 1)];          // [b][h]
    }
  }
  gridbar(cnt, epoch);
  // prologue: attention 0 from init h2
  phase_attn(L, seqs, h2n, energy, ctxP, mP, sP, smem);
  gridbar(cnt, epoch);
  if (blockIdx.x < 64)
    phase_combine(energy, ctxP, mP, sP, ctxQ,
                  attnBase + (size_t)blockIdx.x * Ssteps * Tlen);
  gridbar(cnt, epoch);

  for (int s = 0; s < Ssteps; ++s) {
    int wb = (s & 1), rb = wb ^ 1;
    // W1: LSTM layer 0, K = [emb | ctx | h0]
    phase_lstm<1536,1024>(embQ, 512, ctxQ, 1024, h0Q + rb*HB,
                          wih0, whh0, bih0, bhh0, c0T, h0Q + wb*HB, nullptr, smem);
    gridbar(cnt, epoch);
    // W2: LSTM layer 1
    phase_lstm<1024,512>(h0Q + wb*HB, 512, h1Q + rb*HB, 1024, nullptr,
                         wih1, whh1, bih1, bhh1, c1T, h1Q + wb*HB, nullptr, smem);
    gridbar(cnt, epoch);
    // W3: LSTM layer 2 (+ h2 in [b][h] for attention)
    phase_lstm<1024,512>(h1Q + wb*HB, 512, h2Q + rb*HB, 1024, nullptr,
                         wih2, whh2, bih2, bhh2, c2T, h2Q + wb*HB, h2n, smem);
    gridbar(cnt, epoch);
    // W4: fc-z(s) on blocks 192..255  ||  fused attention(s+1) on blocks 0..191
    if (blockIdx.x >= 192) phase_fcz(h2Q + wb*HB, ctxQ, fcW, fcB, zn, smem);
    else if (s + 1 < Ssteps) phase_attn(L, seqs, h2n, energy, ctxP, mP, sP, smem);
    gridbar(cnt, epoch);
    // W5: combine(s+1) on blocks 0..63  ||  pred+argmax(s) on blocks 64..127
    if (blockIdx.x < 64) {
      if (s + 1 < Ssteps)
        phase_combine(energy, ctxP, mP, sP, ctxQ,
                      attnBase + (size_t)blockIdx.x * Ssteps * Tlen + (size_t)(s+1) * Tlen);
    } else if (blockIdx.x < 128) {
      phase_pred(zn, embW, unembB, out, embQ, s, blockIdx.x - 64, smem);
    }
    gridbar(cnt, epoch);
  }
}

extern "C" void kernel_launch(void* const* d_in, const int* in_sizes, int n_in,
                              void* d_out, int out_size, void* d_ws, size_t ws_size,
                              hipStream_t stream) {
  if (ws_size < (size_t)(OFF_CNT + 16) * 4) return;
  const float* L      = (const float*)d_in[0];
  const int*   seqs   = (const int*)d_in[1];
  const float* embW   = (const float*)d_in[3];
  const float* unembB = (const float*)d_in[4];
  const float* fcW    = (const float*)d_in[5];
  const float* fcB    = (const float*)d_in[6];
  const float* wih0 = (const float*)d_in[7];
  const float* whh0 = (const float*)d_in[8];
  const float* bih0 = (const float*)d_in[9];
  const float* bhh0 = (const float*)d_in[10];
  const float* ih0  = (const float*)d_in[11];
  const float* ic0  = (const float*)d_in[12];
  const float* wih1 = (const float*)d_in[13];
  const float* whh1 = (const float*)d_in[14];
  const float* bih1 = (const float*)d_in[15];
  const float* bhh1 = (const float*)d_in[16];
  const float* ih1  = (const float*)d_in[17];
  const float* ic1  = (const float*)d_in[18];
  const float* wih2 = (const float*)d_in[19];
  const float* whh2 = (const float*)d_in[20];
  const float* bih2 = (const float*)d_in[21];
  const float* bhh2 = (const float*)d_in[22];
  const float* ih2  = (const float*)d_in[23];
  const float* ic2  = (const float*)d_in[24];
  float* out = (float*)d_out;
  float* ws  = (float*)d_ws;
  hipMemsetAsync((char*)d_ws + (size_t)OFF_CNT * 4, 0, 64, stream);
  hipLaunchKernelGGL(speller_kernel, dim3(NBLK), dim3(NTHR), 0, stream,
                     L, seqs, embW, unembB, fcW, fcB,
                     wih0, whh0, bih0, bhh0, ih0, ic0,
                     wih1, whh1, bih1, bhh1, ih1, ic1,
                     wih2, whh2, bih2, bhh2, ih2, ic2,
                     out, ws);
}

// Round 4
// 37125.174 us; speedup vs baseline: 2.2457x; 2.0629x over previous
//
#include <hip/hip_runtime.h>
#include <math.h>

#define Bsz 64
#define Tlen 600
#define Hd 512
#define Vv 33
#define Ssteps 250
#define NBLK 256
#define NTHR 512
#define NWAVE 8
#define HB (Hd*Bsz)   // 32768

// ws offsets (floats)
#define OFF_ENERGY 0                 // [2][64][600]
#define OFF_CTXP   76800             // [2][3][128][64][4]
#define OFF_MP     273408            // [2][192]
#define OFF_SP     273792            // [2][192]
#define OFF_ZNQ    274176            // [128][64][4]
#define OFF_H0Q    306944            // [2][HB]
#define OFF_H1Q    372480
#define OFF_H2Q    438016
#define OFF_C0     503552
#define OFF_C1     536320
#define OFF_C2     569088
#define OFF_H2N    601856            // [b][h]
#define OFF_G0     634624            // [2048][33]
#define OFF_BAR    702208            // 1024 ints
#define WS_NEED    703232

__device__ __forceinline__ float sigm(float x) { return 1.0f / (1.0f + expf(-x)); }
__device__ __forceinline__ float fma4(float4 w, float4 x, float a) {
  return fmaf(w.w, x.w, fmaf(w.z, x.z, fmaf(w.y, x.y, fmaf(w.x, x.x, a))));
}

// Two-level monotonic tree barrier: 16 arrival lines x 16 blocks -> root -> release.
// Arrivals ACQ_REL; waiters poll RELAXED (no per-poll cache inv) + one acquire fence.
__device__ __forceinline__ void gridbar(int* bar, int& epoch) {
  __syncthreads();
  if (threadIdx.x == 0) {
    int g = blockIdx.x & 15;
    int old = __hip_atomic_fetch_add(bar + g * 32, 1, __ATOMIC_ACQ_REL, __HIP_MEMORY_SCOPE_AGENT);
    if (old == epoch * 16 + 15) {
      int r = __hip_atomic_fetch_add(bar + 512, 1, __ATOMIC_ACQ_REL, __HIP_MEMORY_SCOPE_AGENT);
      if (r == epoch * 16 + 15)
        __hip_atomic_fetch_add(bar + 544, 1, __ATOMIC_ACQ_REL, __HIP_MEMORY_SCOPE_AGENT);
    }
    while (__hip_atomic_load(bar + 544, __ATOMIC_RELAXED, __HIP_MEMORY_SCOPE_AGENT) <= epoch)
      __builtin_amdgcn_s_sleep(2);
    __builtin_amdgcn_fence(__ATOMIC_ACQUIRE, "agent");
  }
  epoch++;
  __syncthreads();
}

// Fused energy + online-softmax + unnormalized-context partials; blocks 0..191.
__device__ void phase_attn(const float* __restrict__ L, const int* __restrict__ seqs,
                           const float* __restrict__ h2n, float* __restrict__ energy,
                           float* __restrict__ ctxPq, float* __restrict__ mP,
                           float* __restrict__ sP, float* lred, float* aux) {
  int blk = blockIdx.x;
  if (blk >= 192) return;
  int b = blk & 63, ch = blk >> 6;
  int wv = threadIdx.x >> 6, lane = threadIdx.x & 63;
  int k0 = lane * 8;
  const float4* hq = (const float4*)(h2n + (size_t)b * Hd + k0);
  float4 q0 = hq[0], q1 = hq[1];
  int sq = seqs[b];
  int t0 = ch * 200;
  int tStop = min(t0 + 200, sq);
  float m = -1e30f, ss = 0.f;
  float4 ca0 = {0,0,0,0}, ca1 = {0,0,0,0};
  int t = t0 + wv;
  for (; t < tStop; t += NWAVE) {
    const float4* Lr = (const float4*)(L + ((size_t)b * Tlen + t) * Hd + k0);
    float4 a0 = Lr[0], a1 = Lr[1];
    float d = a0.x*q0.x + a0.y*q0.y + a0.z*q0.z + a0.w*q0.w
            + a1.x*q1.x + a1.y*q1.y + a1.z*q1.z + a1.w*q1.w;
    #pragma unroll
    for (int off = 32; off > 0; off >>= 1) d += __shfl_xor(d, off, 64);
    if (lane == 0) energy[b * Tlen + t] = d;
    float m2 = fmaxf(m, d);
    float sc = expf(m - m2);
    float p = expf(d - m2);
    ss = ss * sc + p;
    ca0.x = ca0.x*sc + p*a0.x; ca0.y = ca0.y*sc + p*a0.y;
    ca0.z = ca0.z*sc + p*a0.z; ca0.w = ca0.w*sc + p*a0.w;
    ca1.x = ca1.x*sc + p*a1.x; ca1.y = ca1.y*sc + p*a1.y;
    ca1.z = ca1.z*sc + p*a1.z; ca1.w = ca1.w*sc + p*a1.w;
    m = m2;
  }
  for (; t < t0 + 200; t += NWAVE)
    if (lane == 0) energy[b * Tlen + t] = -1e9f;
  if (lane == 0) { aux[wv] = m; aux[8 + wv] = ss; }
  *(float4*)(lred + wv * Hd + k0) = ca0;
  *(float4*)(lred + wv * Hd + k0 + 4) = ca1;
  __syncthreads();
  int h = threadIdx.x;
  float M = aux[0];
  #pragma unroll
  for (int w = 1; w < NWAVE; ++w) M = fmaxf(M, aux[w]);
  float S = 0.f, cx = 0.f;
  #pragma unroll
  for (int w = 0; w < NWAVE; ++w) {
    float e = expf(aux[w] - M);
    S += e * aux[8 + w];
    cx += e * lred[w * Hd + h];
  }
  ctxPq[ch * HB + (h >> 2) * 256 + b * 4 + (h & 3)] = cx;
  if (threadIdx.x == 0) { mP[ch * 64 + b] = M; sP[ch * 64 + b] = S; }
}

// logits[64][33] from znQ (staged through LDS) + embS; every block, deterministic.
__device__ void compute_logits(const float* __restrict__ znQ, const float* embS,
                               const float* __restrict__ unembB, float* lred, float* pl) {
  int tid = threadIdx.x, wv = tid >> 6, lane = tid & 63;
  int nv = (wv == 0) ? 5 : 4;
  float acc[5] = {0,0,0,0,0};
  for (int ck = 0; ck < 8; ++ck) {
    __syncthreads();
    for (int i4 = tid; i4 < 1024; i4 += NTHR)
      ((float4*)lred)[i4] = ((const float4*)(znQ + ck * 4096))[i4];
    __syncthreads();
    for (int kqi = 0; kqi < 16; ++kqi) {
      float4 xv = *(float4*)(lred + kqi * 256 + lane * 4);
      int kk = (ck * 16 + kqi) * 4;
      #pragma unroll
      for (int i = 0; i < 5; ++i) {
        if (i < nv) {
          int v = wv + 8 * i;
          float4 e4 = *(const float4*)(embS + v * Hd + kk);
          acc[i] = fma4(e4, xv, acc[i]);
        }
      }
    }
  }
  for (int i = 0; i < nv; ++i) {
    int v = wv + 8 * i;
    pl[v * 64 + lane] = acc[i] + unembB[v];
  }
  __syncthreads();
}

// LSTM layer 0: K = [ctx(deferred 3-partial combine) | h0]; + G0 column for emb.
__device__ void phase_lstm0(const float* __restrict__ ctxPq, const float* __restrict__ mP,
                            const float* __restrict__ sP, const float* __restrict__ h0Qr,
                            const float* __restrict__ wih0, const float* __restrict__ whh0,
                            const float* __restrict__ bih0, const float* __restrict__ bhh0,
                            const float* __restrict__ G0, const int* wordS,
                            float* __restrict__ cT, float* __restrict__ hQw,
                            float* lred, float* gv) {
  int h0c = blockIdx.x * 2;
  int tid = threadIdx.x, lane = tid & 63;
  int wv = __builtin_amdgcn_readfirstlane(tid >> 6);
  float m0 = mP[lane], m1 = mP[64 + lane], m2 = mP[128 + lane];
  float M = fmaxf(m0, fmaxf(m1, m2));
  float e0 = expf(m0 - M), e1 = expf(m1 - M), e2 = expf(m2 - M);
  float inv = 1.0f / (e0 * sP[lane] + e1 * sP[64 + lane] + e2 * sP[128 + lane]);
  float accC[8] = {0,0,0,0,0,0,0,0}, accH[8] = {0,0,0,0,0,0,0,0};
  for (int kqi = 0; kqi < 16; ++kqi) {
    int kq = wv * 16 + kqi;
    float4 p0 = *(const float4*)(ctxPq + kq * 256 + lane * 4);
    float4 p1 = *(const float4*)(ctxPq + HB + kq * 256 + lane * 4);
    float4 p2 = *(const float4*)(ctxPq + 2 * HB + kq * 256 + lane * 4);
    float4 xv;
    xv.x = e0*p0.x + e1*p1.x + e2*p2.x;
    xv.y = e0*p0.y + e1*p1.y + e2*p2.y;
    xv.z = e0*p0.z + e1*p1.z + e2*p2.z;
    xv.w = e0*p0.w + e1*p1.w + e2*p2.w;
    float4 xh = *(const float4*)(h0Qr + kq * 256 + lane * 4);
    #pragma unroll
    for (int jj = 0; jj < 8; ++jj) {
      int j = (jj >> 1) * Hd + h0c + (jj & 1);
      float4 wc = *(const float4*)(wih0 + (size_t)j * 1024 + 512 + kq * 4);
      float4 wh = *(const float4*)(whh0 + (size_t)j * Hd + kq * 4);
      accC[jj] = fma4(wc, xv, accC[jj]);
      accH[jj] = fma4(wh, xh, accH[jj]);
    }
  }
  #pragma unroll
  for (int jj = 0; jj < 8; ++jj)
    lred[(tid >> 6) * 512 + jj * 64 + lane] = accH[jj] + inv * accC[jj];
  __syncthreads();
  int jj2 = tid >> 6, b2 = tid & 63;
  float g = 0.f;
  #pragma unroll
  for (int w = 0; w < NWAVE; ++w) g += lred[w * 512 + jj2 * 64 + b2];
  int j2 = (jj2 >> 1) * Hd + h0c + (jj2 & 1);
  g += bih0[j2] + bhh0[j2] + G0[(size_t)j2 * 33 + wordS[b2]];
  gv[jj2 * 64 + b2] = g;
  __syncthreads();
  if (tid < 128) {
    int hh = tid >> 6, b3 = tid & 63;
    float gi = sigm (gv[(0*2+hh)*64 + b3]);
    float gf = sigm (gv[(1*2+hh)*64 + b3]);
    float gg = tanhf(gv[(2*2+hh)*64 + b3]);
    float go = sigm (gv[(3*2+hh)*64 + b3]);
    int h = h0c + hh;
    float c = cT[h * Bsz + b3];
    float c2 = gf * c + gi * gg;
    float hv = go * tanhf(c2);
    cT[h * Bsz + b3] = c2;
    hQw[(h >> 2) * 256 + b3 * 4 + (h & 3)] = hv;
  }
}

// LSTM layers 1/2: K = [xA(512) | xB(512)], both weight row-lengths 512.
__device__ void phase_lstm12(const float* __restrict__ xAq, const float* __restrict__ xBq,
                             const float* __restrict__ wih, const float* __restrict__ whh,
                             const float* __restrict__ bih, const float* __restrict__ bhh,
                             float* __restrict__ cT, float* __restrict__ hQw,
                             float* __restrict__ hNout, float* lred, float* gv) {
  int h0c = blockIdx.x * 2;
  int tid = threadIdx.x, lane = tid & 63;
  int wv = __builtin_amdgcn_readfirstlane(tid >> 6);
  float acc[8] = {0,0,0,0,0,0,0,0};
  const float* xs = (wv < 4) ? xAq : xBq;
  const float* wb_ = (wv < 4) ? wih : whh;
  int kb = (wv & 3) * 32;
  for (int kqi = 0; kqi < 32; ++kqi) {
    int kq = kb + kqi;
    float4 xv = *(const float4*)(xs + kq * 256 + lane * 4);
    #pragma unroll
    for (int jj = 0; jj < 8; ++jj) {
      int j = (jj >> 1) * Hd + h0c + (jj & 1);
      float4 w4 = *(const float4*)(wb_ + (size_t)j * Hd + kq * 4);
      acc[jj] = fma4(w4, xv, acc[jj]);
    }
  }
  #pragma unroll
  for (int jj = 0; jj < 8; ++jj)
    lred[(tid >> 6) * 512 + jj * 64 + lane] = acc[jj];
  __syncthreads();
  int jj2 = tid >> 6, b2 = tid & 63;
  float g = 0.f;
  #pragma unroll
  for (int w = 0; w < NWAVE; ++w) g += lred[w * 512 + jj2 * 64 + b2];
  int j2 = (jj2 >> 1) * Hd + h0c + (jj2 & 1);
  g += bih[j2] + bhh[j2];
  gv[jj2 * 64 + b2] = g;
  __syncthreads();
  if (tid < 128) {
    int hh = tid >> 6, b3 = tid & 63;
    float gi = sigm (gv[(0*2+hh)*64 + b3]);
    float gf = sigm (gv[(1*2+hh)*64 + b3]);
    float gg = tanhf(gv[(2*2+hh)*64 + b3]);
    float go = sigm (gv[(3*2+hh)*64 + b3]);
    int h = h0c + hh;
    float c = cT[h * Bsz + b3];
    float c2 = gf * c + gi * gg;
    float hv = go * tanhf(c2);
    cT[h * Bsz + b3] = c2;
    hQw[(h >> 2) * 256 + b3 * 4 + (h & 3)] = hv;
    if (hNout) hNout[(size_t)b3 * Hd + h] = hv;
  }
}

// fc + LeakyReLU -> znQ; blocks 192..255, 8 rows each; ctx via deferred combine.
__device__ void phase_fcz(const float* __restrict__ h2Qr, const float* __restrict__ ctxPq,
                          const float* __restrict__ mP, const float* __restrict__ sP,
                          const float* __restrict__ fcW, const float* __restrict__ fcB,
                          float* __restrict__ znQ, float* lred, float* gv) {
  int i0 = (blockIdx.x - 192) * 8;
  int tid = threadIdx.x, lane = tid & 63;
  int wv = __builtin_amdgcn_readfirstlane(tid >> 6);
  float acc[8] = {0,0,0,0,0,0,0,0};
  if (wv < 4) {
    int kb = wv * 32;
    for (int kqi = 0; kqi < 32; ++kqi) {
      int kq = kb + kqi;
      float4 xv = *(const float4*)(h2Qr + kq * 256 + lane * 4);
      #pragma unroll
      for (int jj = 0; jj < 8; ++jj) {
        float4 w4 = *(const float4*)(fcW + (size_t)(i0 + jj) * 1024 + kq * 4);
        acc[jj] = fma4(w4, xv, acc[jj]);
      }
    }
  } else {
    float m0 = mP[lane], m1 = mP[64 + lane], m2 = mP[128 + lane];
    float M = fmaxf(m0, fmaxf(m1, m2));
    float e0 = expf(m0 - M), e1 = expf(m1 - M), e2 = expf(m2 - M);
    float inv = 1.0f / (e0 * sP[lane] + e1 * sP[64 + lane] + e2 * sP[128 + lane]);
    int kb = (wv - 4) * 32;
    for (int kqi = 0; kqi < 32; ++kqi) {
      int kq = kb + kqi;
      float4 p0 = *(const float4*)(ctxPq + kq * 256 + lane * 4);
      float4 p1 = *(const float4*)(ctxPq + HB + kq * 256 + lane * 4);
      float4 p2 = *(const float4*)(ctxPq + 2 * HB + kq * 256 + lane * 4);
      float4 xv;
      xv.x = e0*p0.x + e1*p1.x + e2*p2.x;
      xv.y = e0*p0.y + e1*p1.y + e2*p2.y;
      xv.z = e0*p0.z + e1*p1.z + e2*p2.z;
      xv.w = e0*p0.w + e1*p1.w + e2*p2.w;
      #pragma unroll
      for (int jj = 0; jj < 8; ++jj) {
        float4 w4 = *(const float4*)(fcW + (size_t)(i0 + jj) * 1024 + 512 + kq * 4);
        acc[jj] = fma4(w4, xv, acc[jj]);
      }
    }
    #pragma unroll
    for (int jj = 0; jj < 8; ++jj) acc[jj] *= inv;
  }
  #pragma unroll
  for (int jj = 0; jj < 8; ++jj)
    lred[(tid >> 6) * 512 + jj * 64 + lane] = acc[jj];
  __syncthreads();
  int jj2 = tid >> 6, b2 = tid & 63;
  float z = 0.f;
  #pragma unroll
  for (int w = 0; w < NWAVE; ++w) z += lred[w * 512 + jj2 * 64 + b2];
  z += fcB[i0 + jj2];
  z = (z >= 0.f) ? z : 0.2f * z;
  int r = i0 + jj2;
  znQ[(r >> 2) * 256 + b2 * 4 + (r & 3)] = z;
}

extern "C" __global__ void __launch_bounds__(NTHR)
speller_kernel(const float* __restrict__ L, const int* __restrict__ seqs,
               const float* __restrict__ embW, const float* __restrict__ unembB,
               const float* __restrict__ fcW, const float* __restrict__ fcB,
               const float* __restrict__ wih0, const float* __restrict__ whh0,
               const float* __restrict__ bih0, const float* __restrict__ bhh0,
               const float* __restrict__ ih0, const float* __restrict__ ic0,
               const float* __restrict__ wih1, const float* __restrict__ whh1,
               const float* __restrict__ bih1, const float* __restrict__ bhh1,
               const float* __restrict__ ih1, const float* __restrict__ ic1,
               const float* __restrict__ wih2, const float* __restrict__ whh2,
               const float* __restrict__ bih2, const float* __restrict__ bhh2,
               const float* __restrict__ ih2, const float* __restrict__ ic2,
               float* __restrict__ out, float* __restrict__ ws) {
  __shared__ float embS[16896];
  __shared__ float lred[4096];
  __shared__ float gv[512];
  __shared__ float pl[2112];
  __shared__ float aux[16];
  __shared__ int wordS[64];

  int epoch = 0;
  int tid = threadIdx.x, blk = blockIdx.x;
  float* h0Q = ws + OFF_H0Q;
  float* h1Q = ws + OFF_H1Q;
  float* h2Q = ws + OFF_H2Q;
  float* c0T = ws + OFF_C0;
  float* c1T = ws + OFF_C1;
  float* c2T = ws + OFF_C2;
  float* h2n = ws + OFF_H2N;
  float* znQ = ws + OFF_ZNQ;
  float* G0  = ws + OFF_G0;
  int* bar   = (int*)(ws + OFF_BAR);
  float* attnBase = out + (size_t)Bsz * Ssteps * Vv;

  // ---- init ----
  for (int i = tid; i < 16896; i += NTHR) embS[i] = embW[i];
  __syncthreads();
  {
    int gid = blk * NTHR + tid;
    for (int i = gid; i < HB; i += NBLK * NTHR) {
      int kq_ = (i >> 8) * 4 + (i & 3);
      int h = i >> 6;
      h0Q[HB + i] = ih0[kq_];
      h1Q[HB + i] = ih1[kq_];
      h2Q[HB + i] = ih2[kq_];
      c0T[i] = ic0[h];
      c1T[i] = ic1[h];
      c2T[i] = ic2[h];
      h2n[i] = ih2[i & (Hd - 1)];
    }
    // G0[j][v] = dot(wih0[j, 0:512], embW[v])  for this block's 8 rows
    int wv = tid >> 6, lane = tid & 63;
    int j = blk * 8 + wv;
    const float4* wr = (const float4*)(wih0 + (size_t)j * 1024 + lane * 8);
    float4 w0 = wr[0], w1 = wr[1];
    for (int v = 0; v < Vv; ++v) {
      const float4* er = (const float4*)(embS + v * Hd + lane * 8);
      float4 e0 = er[0], e1 = er[1];
      float d = w0.x*e0.x + w0.y*e0.y + w0.z*e0.z + w0.w*e0.w
              + w1.x*e1.x + w1.y*e1.y + w1.z*e1.z + w1.w*e1.w;
      #pragma unroll
      for (int off = 32; off > 0; off >>= 1) d += __shfl_xor(d, off, 64);
      if (lane == 0) G0[(size_t)j * 33 + v] = d;
    }
  }
  gridbar(bar, epoch);
  // ---- prologue: attention for s=0 (parity 0) ----
  phase_attn(L, seqs, h2n, ws + OFF_ENERGY, ws + OFF_CTXP,
             ws + OFF_MP, ws + OFF_SP, lred, aux);
  gridbar(bar, epoch);

  for (int s = 0; s < Ssteps; ++s) {
    int wb = s & 1, rb = wb ^ 1, ps = s & 1, pn = ps ^ 1;
    float* eng  = ws + OFF_ENERGY + ps * 38400;
    float* ctxP = ws + OFF_CTXP + ps * (3 * HB);
    float* mP   = ws + OFF_MP + ps * 192;
    float* sP   = ws + OFF_SP + ps * 192;
    // ---- phase A ----
    if (blk >= 128 && blk < 192) {   // attn row (s) writer
      int b = blk - 128;
      float m0 = mP[b], m1 = mP[64 + b], m2 = mP[128 + b];
      float M = fmaxf(m0, fmaxf(m1, m2));
      float e0 = expf(m0 - M), e1 = expf(m1 - M), e2 = expf(m2 - M);
      float inv = 1.0f / (e0 * sP[b] + e1 * sP[64 + b] + e2 * sP[128 + b]);
      float* row = attnBase + (size_t)b * Ssteps * Tlen + (size_t)s * Tlen;
      for (int t = tid; t < Tlen; t += NTHR)
        row[t] = expf(eng[b * Tlen + t] - M) * inv;
    }
    if (s > 0) {
      compute_logits(znQ, embS, unembB, lred, pl);
      if (tid < 64) {
        float bv = pl[tid]; int best = 0;
        for (int v = 1; v < Vv; ++v) {
          float x = pl[v * 64 + tid];
          if (x > bv) { bv = x; best = v; }
        }
        wordS[tid] = best;
      }
      __syncthreads();
      if (blk >= 64 && blk < 128 && tid < Vv)   // preds(s-1) writer
        out[(size_t)(blk - 64) * Ssteps * Vv + (size_t)(s - 1) * Vv + tid] = pl[tid * 64 + (blk - 64)];
    } else {
      if (tid < 64) wordS[tid] = 0;
      __syncthreads();
    }
    phase_lstm0(ctxP, mP, sP, h0Q + rb * HB, wih0, whh0, bih0, bhh0,
                G0, wordS, c0T, h0Q + wb * HB, lred, gv);
    gridbar(bar, epoch);
    // ---- phase B ----
    phase_lstm12(h0Q + wb * HB, h1Q + rb * HB, wih1, whh1, bih1, bhh1,
                 c1T, h1Q + wb * HB, nullptr, lred, gv);
    gridbar(bar, epoch);
    // ---- phase C ----
    phase_lstm12(h1Q + wb * HB, h2Q + rb * HB, wih2, whh2, bih2, bhh2,
                 c2T, h2Q + wb * HB, h2n, lred, gv);
    gridbar(bar, epoch);
    // ---- phase D: attn(s+1) [0..191] || fc(s) [192..255] ----
    if (blk < 192) {
      if (s + 1 < Ssteps)
        phase_attn(L, seqs, h2n, ws + OFF_ENERGY + pn * 38400,
                   ws + OFF_CTXP + pn * (3 * HB), ws + OFF_MP + pn * 192,
                   ws + OFF_SP + pn * 192, lred, aux);
    } else {
      phase_fcz(h2Q + wb * HB, ctxP, mP, sP, fcW, fcB, znQ, lred, gv);
    }
    gridbar(bar, epoch);
  }
  // ---- epilogue: preds(249) ----
  compute_logits(znQ, embS, unembB, lred, pl);
  if (blk >= 64 && blk < 128 && tid < Vv)
    out[(size_t)(blk - 64) * Ssteps * Vv + (size_t)(Ssteps - 1) * Vv + tid] = pl[tid * 64 + (blk - 64)];
}

extern "C" void kernel_launch(void* const* d_in, const int* in_sizes, int n_in,
                              void* d_out, int out_size, void* d_ws, size_t ws_size,
                              hipStream_t stream) {
  if (ws_size < (size_t)WS_NEED * 4) return;
  const float* L      = (const float*)d_in[0];
  const int*   seqs   = (const int*)d_in[1];
  const float* embW   = (const float*)d_in[3];
  const float* unembB = (const float*)d_in[4];
  const float* fcW    = (const float*)d_in[5];
  const float* fcB    = (const float*)d_in[6];
  const float* wih0 = (const float*)d_in[7];
  const float* whh0 = (const float*)d_in[8];
  const float* bih0 = (const float*)d_in[9];
  const float* bhh0 = (const float*)d_in[10];
  const float* ih0  = (const float*)d_in[11];
  const float* ic0  = (const float*)d_in[12];
  const float* wih1 = (const float*)d_in[13];
  const float* whh1 = (const float*)d_in[14];
  const float* bih1 = (const float*)d_in[15];
  const float* bhh1 = (const float*)d_in[16];
  const float* ih1  = (const float*)d_in[17];
  const float* ic1  = (const float*)d_in[18];
  const float* wih2 = (const float*)d_in[19];
  const float* whh2 = (const float*)d_in[20];
  const float* bih2 = (const float*)d_in[21];
  const float* bhh2 = (const float*)d_in[22];
  const float* ih2  = (const float*)d_in[23];
  const float* ic2  = (const float*)d_in[24];
  float* out = (float*)d_out;
  float* ws  = (float*)d_ws;
  hipMemsetAsync((char*)d_ws + (size_t)OFF_BAR * 4, 0, 4096, stream);
  hipLaunchKernelGGL(speller_kernel, dim3(NBLK), dim3(NTHR), 0, stream,
                     L, seqs, embW, unembB, fcW, fcB,
                     wih0, whh0, bih0, bhh0, ih0, ic0,
                     wih1, whh1, bih1, bhh1, ih1, ic1,
                     wih2, whh2, bih2, bhh2, ih2, ic2,
                     out, ws);
}